// Round 3
// baseline (336.016 us; speedup 1.0000x reference)
//
#include <hip/hip_runtime.h>

typedef __attribute__((ext_vector_type(8))) short short8;
typedef __attribute__((ext_vector_type(4))) float f32x4;
typedef __attribute__((ext_vector_type(4))) unsigned int u32x4;
typedef __attribute__((ext_vector_type(2))) unsigned int u32x2;
typedef __attribute__((ext_vector_type(4))) unsigned short u16x4;

#define NHEADS 16
#define DHEAD 64
#define SEQ 2048
#define BATCH 4
#define HD 1024
#define MTOT 8192  // BATCH*SEQ

// RNE f32->bf16 (cold paths)
static __device__ __forceinline__ unsigned short f2b(float x) {
  unsigned u = __builtin_bit_cast(unsigned, x);
  u += 0x7fffu + ((u >> 16) & 1u);
  return (unsigned short)(u >> 16);
}

// round-half-up pack of two f32 -> bf16x2 (<=0.5 ulp, 4 insts; hot paths)
static __device__ __forceinline__ unsigned pk2h(float lo, float hi) {
  unsigned a = __builtin_bit_cast(unsigned, lo) + 0x8000u;
  unsigned b = __builtin_bit_cast(unsigned, hi) + 0x8000u;
  return (a >> 16) | (b & 0xffff0000u);
}

// async global -> LDS, 16B per lane. LDS dst = wave-uniform base + lane*16.
static __device__ __forceinline__ void gll16(const void* g, void* l) {
  __builtin_amdgcn_global_load_lds(
      (const __attribute__((address_space(1))) unsigned int*)g,
      (__attribute__((address_space(3))) unsigned int*)l, 16, 0, 0);
}

// ---------------- f32 -> bf16 conversion (hidden states) ----------------
__global__ void cvt_bf16(const float* __restrict__ src,
                         unsigned short* __restrict__ dst, int n4) {
  int i = blockIdx.x * blockDim.x + threadIdx.x;
  if (i < n4) {
    f32x4 v = ((const f32x4*)src)[i];
    u16x4 o;
    o[0] = f2b(v[0]); o[1] = f2b(v[1]); o[2] = f2b(v[2]); o[3] = f2b(v[3]);
    ((u16x4*)dst)[i] = o;
  }
}

// ---- combined prep: Wq/Wk/Wv -> bf16, wmask = bf16(exp(mask)) ----
#define WQ4 (HD * HD / 4)   // 262144 vec4s per weight matrix
__global__ void prep(const float* __restrict__ Wq, const float* __restrict__ Wk,
                     const float* __restrict__ Wv, const float* __restrict__ mask,
                     unsigned short* __restrict__ Wb,
                     unsigned short* __restrict__ Wm) {
  int i = blockIdx.x * blockDim.x + threadIdx.x;
  if (i < 3 * WQ4) {
    int rg = i / WQ4;
    int idx = i - rg * WQ4;
    const float* src = (rg == 0) ? Wq : (rg == 1) ? Wk : Wv;
    f32x4 v = ((const f32x4*)src)[idx];
    u16x4 o;
    o[0] = f2b(v[0]); o[1] = f2b(v[1]); o[2] = f2b(v[2]); o[3] = f2b(v[3]);
    ((u16x4*)(Wb + (size_t)rg * HD * HD))[idx] = o;
  } else {
    int j = i - 3 * WQ4;            // 0..2047 vec4s of mask
    f32x4 v = ((const f32x4*)mask)[j];
    u16x4 o;
    o[0] = f2b(__expf(v[0])); o[1] = f2b(__expf(v[1]));
    o[2] = f2b(__expf(v[2])); o[3] = f2b(__expf(v[3]));
    ((u16x4*)Wm)[j] = o;
  }
}

// ---------------- fused QKV GEMM: 256x256 8-phase counted-vmcnt ----------
// R9: T3+T4 template (m201). BM=BN=256, BK=64, 512 thr (8 waves, 2Mx4N,
// per-wave 128x64 out), LDS 128KB (2-tile dbuf). 8 phases/iter, 2 K-tiles/
// iter. Per phase: {ds_read quadrant frags | stage one 16KB stripe -> barrier
// -> lgkmcnt(0) -> setprio(1) -> 16 MFMA -> setprio(0) -> barrier}. vmcnt(4)
// only at phases 4/8 (2 stripes stay in flight; never drain to 0).
//
// R10: __launch_bounds__(512, 2). R9 omitted the min-waves arg; compiler
//      defaulted to a 128-VGPR budget and spilled all of acc[8][4] (==128
//      VGPRs) to scratch: WRITE_SIZE 49->115MB, MfmaUtil 13%, dur 149us.
//      (512,2) = 2 waves/SIMD = exactly one 8-wave block/CU -> 256-VGPR cap.
//
// Stage stripes: A split by row bit6 (== quadrant qm), B by row bit5 (== qn).
// Steady-state schedule for iter computing tiles t0(buf0: ph1-4), t1(buf1:
// ph5-8), quadrant order (qm,qn) = (0,0),(0,1),(1,0),(1,1):
//   ph1: stage A1(t1)->buf1   [buf1.A1 last read prev ph7/8 -> free]
//   ph2: stage B1(t1)->buf1   [buf1.B1 last read prev ph6/8]
//   ph3: stage A0(t0+2)->buf0 [buf0.A0 (qm0 rows) read ph1,2 -> done]
//   ph4: stage B0(t0+2)->buf0 [buf0.B0 (qn0 rows) read ph1,3]; vmcnt(4)
//        => all but ph3,ph4 stripes landed => buf1(t1) complete. barrier.
//   ph5: stage A1(t0+2)->buf0 [read ph3,4]   ph6: B1(t0+2)->buf0 [ph2,4]
//   ph7: stage A0(t1+2)->buf1 [read ph5,6]   ph8: B0(t1+2)->buf1 [ph5,7];
//        vmcnt(4) => buf0(t0+2) complete. barrier.
// Prologue: 4 stripes of tile0 + A0,B0 of tile1, vmcnt(4), barrier.
// Tail iter stages k wrapped by &1023 (junk, never computed, in-bounds).
//
// R8 kept: m-slab XCD swizzle (FETCH 211->61MB), gather-side XOR swizzle.
__global__ __launch_bounds__(512, 2) void qkv_gemm(
    const unsigned short* __restrict__ X,
    const unsigned short* __restrict__ Wall,
    const float* __restrict__ bq, const float* __restrict__ bk,
    const float* __restrict__ bv,
    const float* __restrict__ rel,          // [2048][64] f32
    const float* __restrict__ mask,         // [4][2048] f32
    unsigned short* __restrict__ Qo,
    unsigned short* __restrict__ Ko,
    unsigned short* __restrict__ Vt) {
  __shared__ __align__(16) unsigned short As[2][256 * 64];
  __shared__ __align__(16) unsigned short Bs[2][256 * 64];

  const int t = threadIdx.x;           // 0..511
  const int lane = t & 63;
  const int w = t >> 6;                // 0..7
  const int wm = w >> 2;               // 0..1 (M half)
  const int wn = w & 3;                // 0..3 (N strip)

  // XCD swizzle: 4 m-tiles pinned per XCD (2MB X slab, L2-resident);
  // consecutive li share a panel so each W panel is fetched ~once per XCD.
  const int n = blockIdx.x;            // 0..383
  const int xcd = n & 7;
  const int li = n >> 3;               // 0..47
  const int bx = xcd * 4 + (li & 3);   // m-tile 0..31
  const int pp = li >> 2;              // 0..11
  const int by = pp & 3;               // n-tile 0..3
  const int bz = pp >> 2;              // 0=Q 1=K 2=V

  const unsigned short* Wp = Wall + (size_t)bz * HD * HD;
  const int m0 = bx * 256;
  const int n0 = by * 256;

  const int cl = lane & 15;
  const int qd = lane >> 4;
  const int lr = lane >> 3;                              // 0..7
  const int cgl = (((lane & 7) ^ (lane >> 3)) << 3);     // gather swizzle

  f32x4 acc[8][4];
#pragma unroll
  for (int i = 0; i < 8; i++)
#pragma unroll
    for (int j = 0; j < 4; j++) acc[i][j] = (f32x4){0.f, 0.f, 0.f, 0.f};

  // stage one 16KB A-stripe (rows with bit6==q) of k-offset k0 into buf b.
  // LDS slot s at row r holds global chunk s^(r&7) (r&7 == lane>>3 here).
  auto stageA = [&](int b, int q, int k0) {
#pragma unroll
    for (int u = 0; u < 2; u++) {
      int v = w * 2 + u;
      int ar = ((v >> 3) << 7) + (q << 6) + ((v & 7) << 3);
      gll16(X + (size_t)(m0 + ar + lr) * HD + k0 + cgl, &As[b][ar * 64]);
    }
  };
  // B-stripe: rows with bit5==q.
  auto stageB = [&](int b, int q, int k0) {
#pragma unroll
    for (int u = 0; u < 2; u++) {
      int v = w * 2 + u;
      int br = ((v >> 2) << 6) + (q << 5) + ((v & 3) << 3);
      gll16(Wp + (size_t)(n0 + br + lr) * HD + k0 + cgl, &Bs[b][br * 64]);
    }
  };

  short8 af[4][2];   // A frags of current (buf,qm); persist across qn phases

#define PHASE(bi, qm, qn, LOADA, STG)                                          \
  {                                                                            \
    if (LOADA) {                                                               \
      _Pragma("unroll") for (int i = 0; i < 4; i++) {                          \
        int r = wm * 128 + (qm) * 64 + i * 16 + cl;                            \
        const unsigned short* rp = &As[bi][r * 64];                            \
        _Pragma("unroll") for (int ks = 0; ks < 2; ks++)                       \
          af[i][ks] = *(const short8*)(rp + (((ks * 4 + qd) ^ (r & 7)) << 3)); \
      }                                                                        \
    }                                                                          \
    short8 bf[2][2];                                                           \
    _Pragma("unroll") for (int j = 0; j < 2; j++) {                            \
      int r = wn * 64 + (qn) * 32 + j * 16 + cl;                               \
      const unsigned short* rp = &Bs[bi][r * 64];                              \
      _Pragma("unroll") for (int ks = 0; ks < 2; ks++)                         \
        bf[j][ks] = *(const short8*)(rp + (((ks * 4 + qd) ^ (r & 7)) << 3));   \
    }                                                                          \
    STG;                                                                       \
    __builtin_amdgcn_s_barrier();                                              \
    asm volatile("s_waitcnt lgkmcnt(0)");                                      \
    __builtin_amdgcn_sched_barrier(0);                                         \
    __builtin_amdgcn_s_setprio(1);                                             \
    if (bz < 2) {                                                              \
      _Pragma("unroll") for (int i = 0; i < 4; i++)                            \
        _Pragma("unroll") for (int j = 0; j < 2; j++)                          \
          _Pragma("unroll") for (int ks = 0; ks < 2; ks++)                     \
            acc[(qm) * 4 + i][(qn) * 2 + j] =                                  \
                __builtin_amdgcn_mfma_f32_16x16x32_bf16(                       \
                    bf[j][ks], af[i][ks], acc[(qm) * 4 + i][(qn) * 2 + j],     \
                    0, 0, 0);                                                  \
    } else {                                                                   \
      _Pragma("unroll") for (int i = 0; i < 4; i++)                            \
        _Pragma("unroll") for (int j = 0; j < 2; j++)                          \
          _Pragma("unroll") for (int ks = 0; ks < 2; ks++)                     \
            acc[(qm) * 4 + i][(qn) * 2 + j] =                                  \
                __builtin_amdgcn_mfma_f32_16x16x32_bf16(                       \
                    af[i][ks], bf[j][ks], acc[(qm) * 4 + i][(qn) * 2 + j],     \
                    0, 0, 0);                                                  \
    }                                                                          \
    __builtin_amdgcn_s_setprio(0);                                             \
  }

#define PH_END()                    \
  __builtin_amdgcn_s_barrier();     \
  __builtin_amdgcn_sched_barrier(0);

#define PH_VMC()                       \
  __builtin_amdgcn_sched_barrier(0);   \
  asm volatile("s_waitcnt vmcnt(4)");  \
  __builtin_amdgcn_sched_barrier(0);

  // ---- prologue: tile0 (4 stripes) + tile1 A0,B0; keep 2 stripes in flight
  stageA(0, 0, 0);
  stageB(0, 0, 0);
  stageA(0, 1, 0);
  stageB(0, 1, 0);
  stageA(1, 0, 64);
  stageB(1, 0, 64);
  asm volatile("s_waitcnt vmcnt(4)");
  __builtin_amdgcn_s_barrier();
  __builtin_amdgcn_sched_barrier(0);

#pragma unroll 1
  for (int it = 0; it < 8; it++) {
    const int t0k = it * 128;            // k of tile t0=2*it
    const int kB = t0k + 64;             // k of tile t1 (always valid)
    const int kA = (t0k + 128) & 1023;   // k of t0+2 (wraps to junk on tail)
    const int kC = (t0k + 192) & 1023;   // k of t1+2 (wraps to junk on tail)

    PHASE(0, 0, 0, true,  stageA(1, 1, kB));   // ph1
    PH_END();
    PHASE(0, 0, 1, false, stageB(1, 1, kB));   // ph2
    PH_END();
    PHASE(0, 1, 0, true,  stageA(0, 0, kA));   // ph3
    PH_END();
    PHASE(0, 1, 1, false, stageB(0, 0, kA));   // ph4
    PH_VMC();                                  // buf1(t1) complete
    PH_END();
    PHASE(1, 0, 0, true,  stageA(0, 1, kA));   // ph5
    PH_END();
    PHASE(1, 0, 1, false, stageB(0, 1, kA));   // ph6
    PH_END();
    PHASE(1, 1, 0, true,  stageA(1, 0, kC));   // ph7
    PH_END();
    PHASE(1, 1, 1, false, stageB(1, 0, kC));   // ph8
    PH_VMC();                                  // buf0(t0+2) complete
    PH_END();
  }

  // ---- epilogue ----
  if (bz == 2) {
    // normal orientation: acc[mf][nf] = D[m(s)][n(feature)]
    const int hh = (n0 >> 6) + wn;
#pragma unroll
    for (int mf = 0; mf < 8; mf++) {
      int mb = m0 + wm * 128 + mf * 16 + qd * 4;
      int bb = mb >> 11, ssb = mb & (SEQ - 1);
      f32x4 mk = *(const f32x4*)(mask + bb * SEQ + ssb);
      f32x4 w4;
#pragma unroll
      for (int r = 0; r < 4; r++) w4[r] = __expf(mk[r]);
      int colp = (ssb & ~31) | ((ssb & 12) << 1) | (((ssb >> 4) & 1) << 2);
#pragma unroll
      for (int nf = 0; nf < 4; nf++) {
        int feat = n0 + wn * 64 + nf * 16 + cl;
        int dd = nf * 16 + cl;
        float bn = bv[feat];
        u32x2 pk;
        pk[0] = pk2h((acc[mf][nf][0] + bn) * w4[0], (acc[mf][nf][1] + bn) * w4[1]);
        pk[1] = pk2h((acc[mf][nf][2] + bn) * w4[2], (acc[mf][nf][3] + bn) * w4[3]);
        *(u32x2*)(Vt + ((size_t)((bb * NHEADS + hh) * DHEAD + dd)) * SEQ + colp) = pk;
      }
    }
  } else {
    // transposed: acc[mf][nf] = D[n(feature)][m(s)]
    const float* bias = (bz == 0) ? bq : bk;
    unsigned short* Out = (bz == 0) ? Qo : Ko;
    const float qs = (bz == 0) ? 0.125f * 1.4426950408889634f : 1.0f;
    const int hh = (n0 >> 6) + wn;
#pragma unroll
    for (int nf = 0; nf < 4; nf++) {
      int nb = n0 + wn * 64 + nf * 16 + qd * 4;
      f32x4 b4 = *(const f32x4*)(bias + nb);
      int ddb = nf * 16 + qd * 4;
#pragma unroll
      for (int mf = 0; mf < 8; mf++) {
        int s = m0 + wm * 128 + mf * 16 + cl;
        int bb = s >> 11, ss = s & (SEQ - 1);
        f32x4 rl = *(const f32x4*)(rel + ss * DHEAD + ddb);
        float x0 = acc[mf][nf][0] + b4[0];
        float x1 = acc[mf][nf][1] + b4[1];
        float x2 = acc[mf][nf][2] + b4[2];
        float x3 = acc[mf][nf][3] + b4[3];
        float y0 = (x0 * rl[1] - x1 * rl[0]) * qs;
        float y1 = (x1 * rl[1] + x0 * rl[0]) * qs;
        float y2 = (x2 * rl[3] - x3 * rl[2]) * qs;
        float y3 = (x3 * rl[3] + x2 * rl[2]) * qs;
        u32x2 pk;
        pk[0] = pk2h(y0, y1);
        pk[1] = pk2h(y2, y3);
        *(u32x2*)(Out + (((size_t)(bb * NHEADS + hh)) * SEQ + ss) * DHEAD + ddb) = pk;
      }
    }
  }
#undef PHASE
#undef PH_END
#undef PH_VMC
}

// ---------------- flash attention (unchanged) ----------------
// Q: [64][2048][64] bf16 pre-scaled by 0.125*log2e; K: [64][2048][64] bf16;
// Vt: [64][64][2048] bf16 (columns permuted, mask-scaled); wm: [4][2048] bf16.
// out: [4][2048][1024] f32.  Softmax inner op = one exp2 per score.
__global__ __launch_bounds__(256, 2) void attn(
    const unsigned short* __restrict__ Q,
    const unsigned short* __restrict__ K,
    const unsigned short* __restrict__ Vt,
    const unsigned short* __restrict__ wmask,
    float* __restrict__ out) {
  __shared__ __align__(16) unsigned short Ks[2][128 * 64];   // [key][d], swizzled
  __shared__ __align__(16) unsigned short Vs[2][64 * 128];   // [d][key'], swizzled

  const int t = threadIdx.x;
  const int lane = t & 63;
  const int w = t >> 6;

  // XCD swizzle: all 16 q-tiles of a bh on one XCD
  const int n = blockIdx.x;          // 0..1023
  const int xcd = n & 7;
  const int li = n >> 3;             // 0..127
  const int bh = xcd * 8 + (li >> 4);
  const int qt = li & 15;

  const int b = bh >> 4, h = bh & 15;
  const int s0 = qt * 128;
  const unsigned short* Qp = Q + (size_t)bh * SEQ * DHEAD;
  const unsigned short* Kp = K + (size_t)bh * SEQ * DHEAD;
  const unsigned short* Vp = Vt + (size_t)bh * DHEAD * SEQ;
  const unsigned short* wmp = wmask + b * SEQ;

  const int cl = lane & 15;
  const int qd = lane >> 4;

  short8 qf[2][2];
#pragma unroll
  for (int mt = 0; mt < 2; mt++)
#pragma unroll
    for (int ks = 0; ks < 2; ks++)
      qf[mt][ks] = *(const short8*)(Qp + (size_t)(s0 + w * 32 + mt * 16 + cl) * DHEAD +
                                    ks * 32 + qd * 8);

  f32x4 ov[2][4];   // [mt][dt], D[d][q]: q=cl, d rows = dt*16+qd*4+r
  f32x4 ovl[2];     // l accumulator (sum_k w_k p_k), all rows identical
#pragma unroll
  for (int mt = 0; mt < 2; mt++) {
    ovl[mt] = (f32x4){0.f, 0.f, 0.f, 0.f};
#pragma unroll
    for (int dt = 0; dt < 4; dt++) ov[mt][dt] = (f32x4){0.f, 0.f, 0.f, 0.f};
  }

  auto stage = [&](int bi, int kt) {
#pragma unroll
    for (int j = 0; j < 4; j++) {
      int r0 = w * 32 + j * 8;
      int r = r0 + (lane >> 3);
      int c = (lane & 7) ^ (r & 7);
      gll16(Kp + (size_t)(kt + r) * DHEAD + c * 8, &Ks[bi][r0 * 64]);
    }
#pragma unroll
    for (int j = 0; j < 4; j++) {
      int r0 = w * 16 + j * 4;
      int r = r0 + (lane >> 4);
      int c = (lane & 15) ^ (r & 7);
      gll16(Vp + (size_t)r * SEQ + kt + c * 8, &Vs[bi][r0 * 128]);
    }
  };

  stage(0, 0);

  for (int it = 0; it < SEQ / 128; it++) {
    const int kt = it * 128;
    const int bi = it & 1;
    __syncthreads();
    if (it + 1 < SEQ / 128) stage(1 - bi, kt + 128);
    const unsigned short* Ksb = &Ks[bi][0];
    const unsigned short* Vsb = &Vs[bi][0];

    // w A-fragment for l-MFMA: keys in P's permuted k-order
    short8 wf[4];
#pragma unroll
    for (int c = 0; c < 4; c++) {
      u32x2 w0 = *(const u32x2*)(wmp + kt + c * 32 + qd * 4);
      u32x2 w1 = *(const u32x2*)(wmp + kt + c * 32 + 16 + qd * 4);
      u32x4 ww = {w0[0], w0[1], w1[0], w1[1]};
      wf[c] = __builtin_bit_cast(short8, ww);
    }

    // ---- scores: D[m=key][n=q] ----
    f32x4 sc[2][8];
#pragma unroll
    for (int mt = 0; mt < 2; mt++)
#pragma unroll
      for (int nt = 0; nt < 8; nt++) sc[mt][nt] = (f32x4){0.f, 0.f, 0.f, 0.f};
#pragma unroll
    for (int ks = 0; ks < 2; ks++) {
#pragma unroll
      for (int nt = 0; nt < 8; nt++) {
        int krow = nt * 16 + cl;
        short8 kf = *(const short8*)(Ksb + krow * 64 +
                                     (((ks * 4 + qd) ^ (krow & 7)) << 3));
        sc[0][nt] = __builtin_amdgcn_mfma_f32_16x16x32_bf16(kf, qf[0][ks], sc[0][nt], 0, 0, 0);
        sc[1][nt] = __builtin_amdgcn_mfma_f32_16x16x32_bf16(kf, qf[1][ks], sc[1][nt], 0, 0, 0);
      }
    }

    // ---- softmax: p = exp2(s) ----
    unsigned pw[2][8][2];
#pragma unroll
    for (int mt = 0; mt < 2; mt++) {
#pragma unroll
      for (int nt = 0; nt < 8; nt++) {
        float p0 = __builtin_amdgcn_exp2f(sc[mt][nt][0]);
        float p1 = __builtin_amdgcn_exp2f(sc[mt][nt][1]);
        float p2 = __builtin_amdgcn_exp2f(sc[mt][nt][2]);
        float p3 = __builtin_amdgcn_exp2f(sc[mt][nt][3]);
        pw[mt][nt][0] = pk2h(p0, p1);
        pw[mt][nt][1] = pk2h(p2, p3);
      }
    }

    // ---- O += V' * P (permuted k-order; V columns pre-permuted to match) ----
#pragma unroll
    for (int c = 0; c < 4; c++) {
      u32x4 bb0 = {pw[0][2 * c][0], pw[0][2 * c][1], pw[0][2 * c + 1][0], pw[0][2 * c + 1][1]};
      u32x4 bb1 = {pw[1][2 * c][0], pw[1][2 * c][1], pw[1][2 * c + 1][0], pw[1][2 * c + 1][1]};
      short8 bf0 = __builtin_bit_cast(short8, bb0);
      short8 bf1 = __builtin_bit_cast(short8, bb1);
      ovl[0] = __builtin_amdgcn_mfma_f32_16x16x32_bf16(wf[c], bf0, ovl[0], 0, 0, 0);
      ovl[1] = __builtin_amdgcn_mfma_f32_16x16x32_bf16(wf[c], bf1, ovl[1], 0, 0, 0);
#pragma unroll
      for (int dt = 0; dt < 4; dt++) {
        int vrow = dt * 16 + cl;
        short8 vf = *(const short8*)(Vsb + vrow * 128 +
                                     (((c * 4 + qd) ^ (vrow & 7)) << 3));
        ov[0][dt] = __builtin_amdgcn_mfma_f32_16x16x32_bf16(vf, bf0, ov[0][dt], 0, 0, 0);
        ov[1][dt] = __builtin_amdgcn_mfma_f32_16x16x32_bf16(vf, bf1, ov[1][dt], 0, 0, 0);
      }
    }
  }

  // ---- epilogue: O[d][q] / l(q) ----
#pragma unroll
  for (int mt = 0; mt < 2; mt++) {
    float rl = 1.0f / ovl[mt][0];
    int s = s0 + w * 32 + mt * 16 + cl;
    float* ob = out + ((size_t)b * SEQ + s) * HD + h * DHEAD;
#pragma unroll
    for (int dt = 0; dt < 4; dt++) {
      f32x4 o;
      o[0] = ov[mt][dt][0] * rl;
      o[1] = ov[mt][dt][1] * rl;
      o[2] = ov[mt][dt][2] * rl;
      o[3] = ov[mt][dt][3] * rl;
      *(f32x4*)(ob + dt * 16 + qd * 4) = o;
    }
  }
}

extern "C" void kernel_launch(void* const* d_in, const int* in_sizes, int n_in,
                              void* d_out, int out_size, void* d_ws, size_t ws_size,
                              hipStream_t stream) {
  const float* hidden = (const float*)d_in[0];
  const float* mask   = (const float*)d_in[1];
  const float* rel    = (const float*)d_in[2];
  const float* Wq     = (const float*)d_in[3];
  const float* bq     = (const float*)d_in[4];
  const float* Wk     = (const float*)d_in[5];
  const float* bk     = (const float*)d_in[6];
  const float* Wv     = (const float*)d_in[7];
  const float* bv     = (const float*)d_in[8];
  float* out = (float*)d_out;

  unsigned short* Xb = (unsigned short*)d_ws;          // 8192*1024
  unsigned short* Wb = Xb + (size_t)MTOT * HD;         // 3*1024*1024
  unsigned short* Qb = Wb + (size_t)3 * HD * HD;       // 8192*1024
  unsigned short* Kb = Qb + (size_t)MTOT * HD;
  unsigned short* Vb = Kb + (size_t)MTOT * HD;
  unsigned short* Wm = Vb + (size_t)MTOT * HD;         // 4*2048

  {
    int n4 = MTOT * HD / 4;
    cvt_bf16<<<n4 / 256, 256, 0, stream>>>(hidden, Xb, n4);
  }
  prep<<<(3 * WQ4 + BATCH * SEQ / 4) / 256, 256, 0, stream>>>(Wq, Wk, Wv, mask, Wb, Wm);
  qkv_gemm<<<dim3(384), 512, 0, stream>>>(Xb, Wb, bq, bk, bv, rel, mask, Qb, Kb, Vb);
  attn<<<dim3(1024), 256, 0, stream>>>(Qb, Kb, Vb, Wm, out);
}

// Round 4
// 334.224 us; speedup vs baseline: 1.0054x; 1.0054x over previous
//
#include <hip/hip_runtime.h>

typedef __attribute__((ext_vector_type(8))) short short8;
typedef __attribute__((ext_vector_type(4))) float f32x4;
typedef __attribute__((ext_vector_type(4))) unsigned int u32x4;
typedef __attribute__((ext_vector_type(2))) unsigned int u32x2;
typedef __attribute__((ext_vector_type(4))) unsigned short u16x4;

#define NHEADS 16
#define DHEAD 64
#define SEQ 2048
#define BATCH 4
#define HD 1024
#define MTOT 8192  // BATCH*SEQ

// RNE f32->bf16 (cold paths)
static __device__ __forceinline__ unsigned short f2b(float x) {
  unsigned u = __builtin_bit_cast(unsigned, x);
  u += 0x7fffu + ((u >> 16) & 1u);
  return (unsigned short)(u >> 16);
}

// round-half-up pack of two f32 -> bf16x2 (<=0.5 ulp, 4 insts; hot paths)
static __device__ __forceinline__ unsigned pk2h(float lo, float hi) {
  unsigned a = __builtin_bit_cast(unsigned, lo) + 0x8000u;
  unsigned b = __builtin_bit_cast(unsigned, hi) + 0x8000u;
  return (a >> 16) | (b & 0xffff0000u);
}

// async global -> LDS, 16B per lane. LDS dst = wave-uniform base + lane*16.
static __device__ __forceinline__ void gll16(const void* g, void* l) {
  __builtin_amdgcn_global_load_lds(
      (const __attribute__((address_space(1))) unsigned int*)g,
      (__attribute__((address_space(3))) unsigned int*)l, 16, 0, 0);
}

// ---------------- f32 -> bf16 conversion (hidden states) ----------------
__global__ void cvt_bf16(const float* __restrict__ src,
                         unsigned short* __restrict__ dst, int n4) {
  int i = blockIdx.x * blockDim.x + threadIdx.x;
  if (i < n4) {
    f32x4 v = ((const f32x4*)src)[i];
    u16x4 o;
    o[0] = f2b(v[0]); o[1] = f2b(v[1]); o[2] = f2b(v[2]); o[3] = f2b(v[3]);
    ((u16x4*)dst)[i] = o;
  }
}

// ---- combined prep: Wq/Wk/Wv -> bf16, wmask = bf16(exp(mask)) ----
#define WQ4 (HD * HD / 4)   // 262144 vec4s per weight matrix
__global__ void prep(const float* __restrict__ Wq, const float* __restrict__ Wk,
                     const float* __restrict__ Wv, const float* __restrict__ mask,
                     unsigned short* __restrict__ Wb,
                     unsigned short* __restrict__ Wm) {
  int i = blockIdx.x * blockDim.x + threadIdx.x;
  if (i < 3 * WQ4) {
    int rg = i / WQ4;
    int idx = i - rg * WQ4;
    const float* src = (rg == 0) ? Wq : (rg == 1) ? Wk : Wv;
    f32x4 v = ((const f32x4*)src)[idx];
    u16x4 o;
    o[0] = f2b(v[0]); o[1] = f2b(v[1]); o[2] = f2b(v[2]); o[3] = f2b(v[3]);
    ((u16x4*)(Wb + (size_t)rg * HD * HD))[idx] = o;
  } else {
    int j = i - 3 * WQ4;            // 0..2047 vec4s of mask
    f32x4 v = ((const f32x4*)mask)[j];
    u16x4 o;
    o[0] = f2b(__expf(v[0])); o[1] = f2b(__expf(v[1]));
    o[2] = f2b(__expf(v[2])); o[3] = f2b(__expf(v[3]));
    ((u16x4*)Wm)[j] = o;
  }
}

// ---------------- fused QKV GEMM: 256x256 8-phase counted-vmcnt ----------
// R9: T3+T4 template (m201). BM=BN=256, BK=64, 512 thr (8 waves, 2Mx4N,
// per-wave 128x64 out), LDS 128KB (2-tile dbuf). 8 phases/iter, 2 K-tiles/
// iter. Per phase: {ds_read quadrant frags | stage one 16KB stripe -> barrier
// -> lgkmcnt(0) -> setprio(1) -> 16 MFMA -> setprio(0) -> barrier}. vmcnt(4)
// only at phases 4/8 (2 stripes stay in flight; never drain to 0).
//
// R10: __launch_bounds__(512,2) FAILED to lift the VGPR budget — the 2nd
//      launch_bounds arg is only a MIN waves/EU (an upper bound the compiler
//      MAY use); LLVM's occupancy heuristic still targeted 4 waves/EU and
//      crammed into exactly 128 VGPR, spilling acc (WRITE_SIZE 102MB).
// R11: __attribute__((amdgpu_waves_per_eu(2,2))) — pins BOTH min and max to
//      2 waves/EU, forcing the allocator to actually use the 256-VGPR
//      budget. Costs nothing: 128KB LDS already caps us at 1 block/CU
//      (= 2 waves/SIMD).
//
// Stage stripes: A split by row bit6 (== quadrant qm), B by row bit5 (== qn).
// Steady-state schedule for iter computing tiles t0(buf0: ph1-4), t1(buf1:
// ph5-8), quadrant order (qm,qn) = (0,0),(0,1),(1,0),(1,1):
//   ph1: stage A1(t1)->buf1   [buf1.A1 last read prev ph7/8 -> free]
//   ph2: stage B1(t1)->buf1   [buf1.B1 last read prev ph6/8]
//   ph3: stage A0(t0+2)->buf0 [buf0.A0 (qm0 rows) read ph1,2 -> done]
//   ph4: stage B0(t0+2)->buf0 [buf0.B0 (qn0 rows) read ph1,3]; vmcnt(4)
//        => all but ph3,ph4 stripes landed => buf1(t1) complete. barrier.
//   ph5: stage A1(t0+2)->buf0 [read ph3,4]   ph6: B1(t0+2)->buf0 [ph2,4]
//   ph7: stage A0(t1+2)->buf1 [read ph5,6]   ph8: B0(t1+2)->buf1 [ph5,7];
//        vmcnt(4) => buf0(t0+2) complete. barrier.
// Prologue: 4 stripes of tile0 + A0,B0 of tile1, vmcnt(4), barrier.
// Tail iter stages k wrapped by &1023 (junk, never computed, in-bounds).
//
// R8 kept: m-slab XCD swizzle (FETCH 211->61MB), gather-side XOR swizzle.
__global__ __launch_bounds__(512)
__attribute__((amdgpu_waves_per_eu(2, 2))) void qkv_gemm(
    const unsigned short* __restrict__ X,
    const unsigned short* __restrict__ Wall,
    const float* __restrict__ bq, const float* __restrict__ bk,
    const float* __restrict__ bv,
    const float* __restrict__ rel,          // [2048][64] f32
    const float* __restrict__ mask,         // [4][2048] f32
    unsigned short* __restrict__ Qo,
    unsigned short* __restrict__ Ko,
    unsigned short* __restrict__ Vt) {
  __shared__ __align__(16) unsigned short As[2][256 * 64];
  __shared__ __align__(16) unsigned short Bs[2][256 * 64];

  const int t = threadIdx.x;           // 0..511
  const int lane = t & 63;
  const int w = t >> 6;                // 0..7
  const int wm = w >> 2;               // 0..1 (M half)
  const int wn = w & 3;                // 0..3 (N strip)

  // XCD swizzle: 4 m-tiles pinned per XCD (2MB X slab, L2-resident);
  // consecutive li share a panel so each W panel is fetched ~once per XCD.
  const int n = blockIdx.x;            // 0..383
  const int xcd = n & 7;
  const int li = n >> 3;               // 0..47
  const int bx = xcd * 4 + (li & 3);   // m-tile 0..31
  const int pp = li >> 2;              // 0..11
  const int by = pp & 3;               // n-tile 0..3
  const int bz = pp >> 2;              // 0=Q 1=K 2=V

  const unsigned short* Wp = Wall + (size_t)bz * HD * HD;
  const int m0 = bx * 256;
  const int n0 = by * 256;

  const int cl = lane & 15;
  const int qd = lane >> 4;
  const int lr = lane >> 3;                              // 0..7
  const int cgl = (((lane & 7) ^ (lane >> 3)) << 3);     // gather swizzle

  f32x4 acc[8][4];
#pragma unroll
  for (int i = 0; i < 8; i++)
#pragma unroll
    for (int j = 0; j < 4; j++) acc[i][j] = (f32x4){0.f, 0.f, 0.f, 0.f};

  // stage one 16KB A-stripe (rows with bit6==q) of k-offset k0 into buf b.
  // LDS slot s at row r holds global chunk s^(r&7) (r&7 == lane>>3 here).
  auto stageA = [&](int b, int q, int k0) {
#pragma unroll
    for (int u = 0; u < 2; u++) {
      int v = w * 2 + u;
      int ar = ((v >> 3) << 7) + (q << 6) + ((v & 7) << 3);
      gll16(X + (size_t)(m0 + ar + lr) * HD + k0 + cgl, &As[b][ar * 64]);
    }
  };
  // B-stripe: rows with bit5==q.
  auto stageB = [&](int b, int q, int k0) {
#pragma unroll
    for (int u = 0; u < 2; u++) {
      int v = w * 2 + u;
      int br = ((v >> 2) << 6) + (q << 5) + ((v & 3) << 3);
      gll16(Wp + (size_t)(n0 + br + lr) * HD + k0 + cgl, &Bs[b][br * 64]);
    }
  };

  short8 af[4][2];   // A frags of current (buf,qm); persist across qn phases

#define PHASE(bi, qm, qn, LOADA, STG)                                          \
  {                                                                            \
    if (LOADA) {                                                               \
      _Pragma("unroll") for (int i = 0; i < 4; i++) {                          \
        int r = wm * 128 + (qm) * 64 + i * 16 + cl;                            \
        const unsigned short* rp = &As[bi][r * 64];                            \
        _Pragma("unroll") for (int ks = 0; ks < 2; ks++)                       \
          af[i][ks] = *(const short8*)(rp + (((ks * 4 + qd) ^ (r & 7)) << 3)); \
      }                                                                        \
    }                                                                          \
    short8 bf[2][2];                                                           \
    _Pragma("unroll") for (int j = 0; j < 2; j++) {                            \
      int r = wn * 64 + (qn) * 32 + j * 16 + cl;                               \
      const unsigned short* rp = &Bs[bi][r * 64];                              \
      _Pragma("unroll") for (int ks = 0; ks < 2; ks++)                         \
        bf[j][ks] = *(const short8*)(rp + (((ks * 4 + qd) ^ (r & 7)) << 3));   \
    }                                                                          \
    STG;                                                                       \
    __builtin_amdgcn_s_barrier();                                              \
    asm volatile("s_waitcnt lgkmcnt(0)");                                      \
    __builtin_amdgcn_sched_barrier(0);                                         \
    __builtin_amdgcn_s_setprio(1);                                             \
    if (bz < 2) {                                                              \
      _Pragma("unroll") for (int i = 0; i < 4; i++)                            \
        _Pragma("unroll") for (int j = 0; j < 2; j++)                          \
          _Pragma("unroll") for (int ks = 0; ks < 2; ks++)                     \
            acc[(qm) * 4 + i][(qn) * 2 + j] =                                  \
                __builtin_amdgcn_mfma_f32_16x16x32_bf16(                       \
                    bf[j][ks], af[i][ks], acc[(qm) * 4 + i][(qn) * 2 + j],     \
                    0, 0, 0);                                                  \
    } else {                                                                   \
      _Pragma("unroll") for (int i = 0; i < 4; i++)                            \
        _Pragma("unroll") for (int j = 0; j < 2; j++)                          \
          _Pragma("unroll") for (int ks = 0; ks < 2; ks++)                     \
            acc[(qm) * 4 + i][(qn) * 2 + j] =                                  \
                __builtin_amdgcn_mfma_f32_16x16x32_bf16(                       \
                    af[i][ks], bf[j][ks], acc[(qm) * 4 + i][(qn) * 2 + j],     \
                    0, 0, 0);                                                  \
    }                                                                          \
    __builtin_amdgcn_s_setprio(0);                                             \
  }

#define PH_END()                    \
  __builtin_amdgcn_s_barrier();     \
  __builtin_amdgcn_sched_barrier(0);

#define PH_VMC()                       \
  __builtin_amdgcn_sched_barrier(0);   \
  asm volatile("s_waitcnt vmcnt(4)");  \
  __builtin_amdgcn_sched_barrier(0);

  // ---- prologue: tile0 (4 stripes) + tile1 A0,B0; keep 2 stripes in flight
  stageA(0, 0, 0);
  stageB(0, 0, 0);
  stageA(0, 1, 0);
  stageB(0, 1, 0);
  stageA(1, 0, 64);
  stageB(1, 0, 64);
  asm volatile("s_waitcnt vmcnt(4)");
  __builtin_amdgcn_s_barrier();
  __builtin_amdgcn_sched_barrier(0);

#pragma unroll 1
  for (int it = 0; it < 8; it++) {
    const int t0k = it * 128;            // k of tile t0=2*it
    const int kB = t0k + 64;             // k of tile t1 (always valid)
    const int kA = (t0k + 128) & 1023;   // k of t0+2 (wraps to junk on tail)
    const int kC = (t0k + 192) & 1023;   // k of t1+2 (wraps to junk on tail)

    PHASE(0, 0, 0, true,  stageA(1, 1, kB));   // ph1
    PH_END();
    PHASE(0, 0, 1, false, stageB(1, 1, kB));   // ph2
    PH_END();
    PHASE(0, 1, 0, true,  stageA(0, 0, kA));   // ph3
    PH_END();
    PHASE(0, 1, 1, false, stageB(0, 0, kA));   // ph4
    PH_VMC();                                  // buf1(t1) complete
    PH_END();
    PHASE(1, 0, 0, true,  stageA(0, 1, kA));   // ph5
    PH_END();
    PHASE(1, 0, 1, false, stageB(0, 1, kA));   // ph6
    PH_END();
    PHASE(1, 1, 0, true,  stageA(1, 0, kC));   // ph7
    PH_END();
    PHASE(1, 1, 1, false, stageB(1, 0, kC));   // ph8
    PH_VMC();                                  // buf0(t0+2) complete
    PH_END();
  }

  // ---- epilogue ----
  if (bz == 2) {
    // normal orientation: acc[mf][nf] = D[m(s)][n(feature)]
    const int hh = (n0 >> 6) + wn;
#pragma unroll
    for (int mf = 0; mf < 8; mf++) {
      int mb = m0 + wm * 128 + mf * 16 + qd * 4;
      int bb = mb >> 11, ssb = mb & (SEQ - 1);
      f32x4 mk = *(const f32x4*)(mask + bb * SEQ + ssb);
      f32x4 w4;
#pragma unroll
      for (int r = 0; r < 4; r++) w4[r] = __expf(mk[r]);
      int colp = (ssb & ~31) | ((ssb & 12) << 1) | (((ssb >> 4) & 1) << 2);
#pragma unroll
      for (int nf = 0; nf < 4; nf++) {
        int feat = n0 + wn * 64 + nf * 16 + cl;
        int dd = nf * 16 + cl;
        float bn = bv[feat];
        u32x2 pk;
        pk[0] = pk2h((acc[mf][nf][0] + bn) * w4[0], (acc[mf][nf][1] + bn) * w4[1]);
        pk[1] = pk2h((acc[mf][nf][2] + bn) * w4[2], (acc[mf][nf][3] + bn) * w4[3]);
        *(u32x2*)(Vt + ((size_t)((bb * NHEADS + hh) * DHEAD + dd)) * SEQ + colp) = pk;
      }
    }
  } else {
    // transposed: acc[mf][nf] = D[n(feature)][m(s)]
    const float* bias = (bz == 0) ? bq : bk;
    unsigned short* Out = (bz == 0) ? Qo : Ko;
    const float qs = (bz == 0) ? 0.125f * 1.4426950408889634f : 1.0f;
    const int hh = (n0 >> 6) + wn;
#pragma unroll
    for (int nf = 0; nf < 4; nf++) {
      int nb = n0 + wn * 64 + nf * 16 + qd * 4;
      f32x4 b4 = *(const f32x4*)(bias + nb);
      int ddb = nf * 16 + qd * 4;
#pragma unroll
      for (int mf = 0; mf < 8; mf++) {
        int s = m0 + wm * 128 + mf * 16 + cl;
        int bb = s >> 11, ss = s & (SEQ - 1);
        f32x4 rl = *(const f32x4*)(rel + ss * DHEAD + ddb);
        float x0 = acc[mf][nf][0] + b4[0];
        float x1 = acc[mf][nf][1] + b4[1];
        float x2 = acc[mf][nf][2] + b4[2];
        float x3 = acc[mf][nf][3] + b4[3];
        float y0 = (x0 * rl[1] - x1 * rl[0]) * qs;
        float y1 = (x1 * rl[1] + x0 * rl[0]) * qs;
        float y2 = (x2 * rl[3] - x3 * rl[2]) * qs;
        float y3 = (x3 * rl[3] + x2 * rl[2]) * qs;
        u32x2 pk;
        pk[0] = pk2h(y0, y1);
        pk[1] = pk2h(y2, y3);
        *(u32x2*)(Out + (((size_t)(bb * NHEADS + hh)) * SEQ + ss) * DHEAD + ddb) = pk;
      }
    }
  }
#undef PHASE
#undef PH_END
#undef PH_VMC
}

// ---------------- flash attention (unchanged) ----------------
// Q: [64][2048][64] bf16 pre-scaled by 0.125*log2e; K: [64][2048][64] bf16;
// Vt: [64][64][2048] bf16 (columns permuted, mask-scaled); wm: [4][2048] bf16.
// out: [4][2048][1024] f32.  Softmax inner op = one exp2 per score.
__global__ __launch_bounds__(256, 2) void attn(
    const unsigned short* __restrict__ Q,
    const unsigned short* __restrict__ K,
    const unsigned short* __restrict__ Vt,
    const unsigned short* __restrict__ wmask,
    float* __restrict__ out) {
  __shared__ __align__(16) unsigned short Ks[2][128 * 64];   // [key][d], swizzled
  __shared__ __align__(16) unsigned short Vs[2][64 * 128];   // [d][key'], swizzled

  const int t = threadIdx.x;
  const int lane = t & 63;
  const int w = t >> 6;

  // XCD swizzle: all 16 q-tiles of a bh on one XCD
  const int n = blockIdx.x;          // 0..1023
  const int xcd = n & 7;
  const int li = n >> 3;             // 0..127
  const int bh = xcd * 8 + (li >> 4);
  const int qt = li & 15;

  const int b = bh >> 4, h = bh & 15;
  const int s0 = qt * 128;
  const unsigned short* Qp = Q + (size_t)bh * SEQ * DHEAD;
  const unsigned short* Kp = K + (size_t)bh * SEQ * DHEAD;
  const unsigned short* Vp = Vt + (size_t)bh * DHEAD * SEQ;
  const unsigned short* wmp = wmask + b * SEQ;

  const int cl = lane & 15;
  const int qd = lane >> 4;

  short8 qf[2][2];
#pragma unroll
  for (int mt = 0; mt < 2; mt++)
#pragma unroll
    for (int ks = 0; ks < 2; ks++)
      qf[mt][ks] = *(const short8*)(Qp + (size_t)(s0 + w * 32 + mt * 16 + cl) * DHEAD +
                                    ks * 32 + qd * 8);

  f32x4 ov[2][4];   // [mt][dt], D[d][q]: q=cl, d rows = dt*16+qd*4+r
  f32x4 ovl[2];     // l accumulator (sum_k w_k p_k), all rows identical
#pragma unroll
  for (int mt = 0; mt < 2; mt++) {
    ovl[mt] = (f32x4){0.f, 0.f, 0.f, 0.f};
#pragma unroll
    for (int dt = 0; dt < 4; dt++) ov[mt][dt] = (f32x4){0.f, 0.f, 0.f, 0.f};
  }

  auto stage = [&](int bi, int kt) {
#pragma unroll
    for (int j = 0; j < 4; j++) {
      int r0 = w * 32 + j * 8;
      int r = r0 + (lane >> 3);
      int c = (lane & 7) ^ (r & 7);
      gll16(Kp + (size_t)(kt + r) * DHEAD + c * 8, &Ks[bi][r0 * 64]);
    }
#pragma unroll
    for (int j = 0; j < 4; j++) {
      int r0 = w * 16 + j * 4;
      int r = r0 + (lane >> 4);
      int c = (lane & 15) ^ (r & 7);
      gll16(Vp + (size_t)r * SEQ + kt + c * 8, &Vs[bi][r0 * 128]);
    }
  };

  stage(0, 0);

  for (int it = 0; it < SEQ / 128; it++) {
    const int kt = it * 128;
    const int bi = it & 1;
    __syncthreads();
    if (it + 1 < SEQ / 128) stage(1 - bi, kt + 128);
    const unsigned short* Ksb = &Ks[bi][0];
    const unsigned short* Vsb = &Vs[bi][0];

    // w A-fragment for l-MFMA: keys in P's permuted k-order
    short8 wf[4];
#pragma unroll
    for (int c = 0; c < 4; c++) {
      u32x2 w0 = *(const u32x2*)(wmp + kt + c * 32 + qd * 4);
      u32x2 w1 = *(const u32x2*)(wmp + kt + c * 32 + 16 + qd * 4);
      u32x4 ww = {w0[0], w0[1], w1[0], w1[1]};
      wf[c] = __builtin_bit_cast(short8, ww);
    }

    // ---- scores: D[m=key][n=q] ----
    f32x4 sc[2][8];
#pragma unroll
    for (int mt = 0; mt < 2; mt++)
#pragma unroll
      for (int nt = 0; nt < 8; nt++) sc[mt][nt] = (f32x4){0.f, 0.f, 0.f, 0.f};
#pragma unroll
    for (int ks = 0; ks < 2; ks++) {
#pragma unroll
      for (int nt = 0; nt < 8; nt++) {
        int krow = nt * 16 + cl;
        short8 kf = *(const short8*)(Ksb + krow * 64 +
                                     (((ks * 4 + qd) ^ (krow & 7)) << 3));
        sc[0][nt] = __builtin_amdgcn_mfma_f32_16x16x32_bf16(kf, qf[0][ks], sc[0][nt], 0, 0, 0);
        sc[1][nt] = __builtin_amdgcn_mfma_f32_16x16x32_bf16(kf, qf[1][ks], sc[1][nt], 0, 0, 0);
      }
    }

    // ---- softmax: p = exp2(s) ----
    unsigned pw[2][8][2];
#pragma unroll
    for (int mt = 0; mt < 2; mt++) {
#pragma unroll
      for (int nt = 0; nt < 8; nt++) {
        float p0 = __builtin_amdgcn_exp2f(sc[mt][nt][0]);
        float p1 = __builtin_amdgcn_exp2f(sc[mt][nt][1]);
        float p2 = __builtin_amdgcn_exp2f(sc[mt][nt][2]);
        float p3 = __builtin_amdgcn_exp2f(sc[mt][nt][3]);
        pw[mt][nt][0] = pk2h(p0, p1);
        pw[mt][nt][1] = pk2h(p2, p3);
      }
    }

    // ---- O += V' * P (permuted k-order; V columns pre-permuted to match) ----
#pragma unroll
    for (int c = 0; c < 4; c++) {
      u32x4 bb0 = {pw[0][2 * c][0], pw[0][2 * c][1], pw[0][2 * c + 1][0], pw[0][2 * c + 1][1]};
      u32x4 bb1 = {pw[1][2 * c][0], pw[1][2 * c][1], pw[1][2 * c + 1][0], pw[1][2 * c + 1][1]};
      short8 bf0 = __builtin_bit_cast(short8, bb0);
      short8 bf1 = __builtin_bit_cast(short8, bb1);
      ovl[0] = __builtin_amdgcn_mfma_f32_16x16x32_bf16(wf[c], bf0, ovl[0], 0, 0, 0);
      ovl[1] = __builtin_amdgcn_mfma_f32_16x16x32_bf16(wf[c], bf1, ovl[1], 0, 0, 0);
#pragma unroll
      for (int dt = 0; dt < 4; dt++) {
        int vrow = dt * 16 + cl;
        short8 vf = *(const short8*)(Vsb + vrow * 128 +
                                     (((c * 4 + qd) ^ (vrow & 7)) << 3));
        ov[0][dt] = __builtin_amdgcn_mfma_f32_16x16x32_bf16(vf, bf0, ov[0][dt], 0, 0, 0);
        ov[1][dt] = __builtin_amdgcn_mfma_f32_16x16x32_bf16(vf, bf1, ov[1][dt], 0, 0, 0);
      }
    }
  }

  // ---- epilogue: O[d][q] / l(q) ----
#pragma unroll
  for (int mt = 0; mt < 2; mt++) {
    float rl = 1.0f / ovl[mt][0];
    int s = s0 + w * 32 + mt * 16 + cl;
    float* ob = out + ((size_t)b * SEQ + s) * HD + h * DHEAD;
#pragma unroll
    for (int dt = 0; dt < 4; dt++) {
      f32x4 o;
      o[0] = ov[mt][dt][0] * rl;
      o[1] = ov[mt][dt][1] * rl;
      o[2] = ov[mt][dt][2] * rl;
      o[3] = ov[mt][dt][3] * rl;
      *(f32x4*)(ob + dt * 16 + qd * 4) = o;
    }
  }
}

extern "C" void kernel_launch(void* const* d_in, const int* in_sizes, int n_in,
                              void* d_out, int out_size, void* d_ws, size_t ws_size,
                              hipStream_t stream) {
  const float* hidden = (const float*)d_in[0];
  const float* mask   = (const float*)d_in[1];
  const float* rel    = (const float*)d_in[2];
  const float* Wq     = (const float*)d_in[3];
  const float* bq     = (const float*)d_in[4];
  const float* Wk     = (const float*)d_in[5];
  const float* bk     = (const float*)d_in[6];
  const float* Wv     = (const float*)d_in[7];
  const float* bv     = (const float*)d_in[8];
  float* out = (float*)d_out;

  unsigned short* Xb = (unsigned short*)d_ws;          // 8192*1024
  unsigned short* Wb = Xb + (size_t)MTOT * HD;         // 3*1024*1024
  unsigned short* Qb = Wb + (size_t)3 * HD * HD;       // 8192*1024
  unsigned short* Kb = Qb + (size_t)MTOT * HD;
  unsigned short* Vb = Kb + (size_t)MTOT * HD;
  unsigned short* Wm = Vb + (size_t)MTOT * HD;         // 4*2048

  {
    int n4 = MTOT * HD / 4;
    cvt_bf16<<<n4 / 256, 256, 0, stream>>>(hidden, Xb, n4);
  }
  prep<<<(3 * WQ4 + BATCH * SEQ / 4) / 256, 256, 0, stream>>>(Wq, Wk, Wv, mask, Wb, Wm);
  qkv_gemm<<<dim3(384), 512, 0, stream>>>(Xb, Wb, bq, bk, bv, rel, mask, Qb, Kb, Vb);
  attn<<<dim3(1024), 256, 0, stream>>>(Qb, Kb, Vb, Wm, out);
}